// Round 1
// baseline (11006.075 us; speedup 1.0000x reference)
//
#include <hip/hip_runtime.h>
#include <hip/hip_bf16.h>

// Problem constants
#define SHIFT_ 3
#define SCALE_ 0.17677669529663687f   // 32^-0.5
#define NTOK   200704                 // 64*56*56
#define NWIN   4096

static __device__ __forceinline__ float bf2f(unsigned short u) {
    union { unsigned int ui; float f; } v; v.ui = ((unsigned int)u) << 16; return v.f;
}
static __device__ __forceinline__ unsigned short f2bf(float f) {
    union { float f; unsigned int u; } v; v.f = f;
    unsigned int u = v.u;
    unsigned int r = u + 0x7FFFu + ((u >> 16) & 1u);   // RNE
    return (unsigned short)(r >> 16);
}
static __device__ __forceinline__ void bfpair(unsigned int d, float& a, float& b) {
    union { unsigned int u; float f; } lo, hi;
    lo.u = d << 16; hi.u = d & 0xFFFF0000u;
    a = lo.f; b = hi.f;
}
static __device__ __forceinline__ float wsum(float v) {
    #pragma unroll
    for (int o = 32; o; o >>= 1) v += __shfl_xor(v, o);
    return v;
}
static __device__ __forceinline__ float wmax(float v) {
    #pragma unroll
    for (int o = 32; o; o >>= 1) v = fmaxf(v, __shfl_xor(v, o));
    return v;
}

// ---------------------------------------------------------------------------
// K1: LN1 + roll(-3,-3) + window partition.  One wave per DEST token.
// xw[win][t][c] (bf16), win = b*64 + wh*8 + ww, t = i*7 + j
// source pixel: h=(wh*7+i+3)%56, w=(ww*7+j+3)%56
// ---------------------------------------------------------------------------
__global__ __launch_bounds__(256) void k_ln1(const float* __restrict__ x,
                                             const float* __restrict__ nw,
                                             const float* __restrict__ nb,
                                             unsigned short* __restrict__ xw) {
    int tok  = blockIdx.x * 4 + (threadIdx.x >> 6);
    int lane = threadIdx.x & 63;
    int win = tok / 49, t = tok - win * 49;
    int bb = win >> 6, wh = (win >> 3) & 7, ww = win & 7;
    int i = t / 7, j = t - i * 7;
    int h  = wh * 7 + i + SHIFT_; if (h  >= 56) h  -= 56;
    int w2 = ww * 7 + j + SHIFT_; if (w2 >= 56) w2 -= 56;
    const float* src = x + ((size_t)bb * 3136 + h * 56 + w2) * 128;
    float v0 = src[lane], v1 = src[lane + 64];
    float mu = wsum(v0 + v1) * (1.f / 128.f);
    float d0 = v0 - mu, d1 = v1 - mu;
    float var = wsum(d0 * d0 + d1 * d1) * (1.f / 128.f);
    float inv = rsqrtf(var + 1e-5f);
    unsigned short* dst = xw + (size_t)tok * 128;
    dst[lane]      = f2bf(d0 * inv * nw[lane]      + nb[lane]);
    dst[lane + 64] = f2bf(d1 * inv * nw[lane + 64] + nb[lane + 64]);
}

// ---------------------------------------------------------------------------
// K3: LN2 over x2 (= d_out after attention) -> xn (bf16), token order.
// ---------------------------------------------------------------------------
__global__ __launch_bounds__(256) void k_ln2(const float* __restrict__ x2,
                                             const float* __restrict__ nw,
                                             const float* __restrict__ nb,
                                             unsigned short* __restrict__ xn) {
    int tok  = blockIdx.x * 4 + (threadIdx.x >> 6);
    int lane = threadIdx.x & 63;
    const float* src = x2 + (size_t)tok * 128;
    float v0 = src[lane], v1 = src[lane + 64];
    float mu = wsum(v0 + v1) * (1.f / 128.f);
    float d0 = v0 - mu, d1 = v1 - mu;
    float var = wsum(d0 * d0 + d1 * d1) * (1.f / 128.f);
    float inv = rsqrtf(var + 1e-5f);
    unsigned short* dst = xn + (size_t)tok * 128;
    dst[lane]      = f2bf(d0 * inv * nw[lane]      + nb[lane]);
    dst[lane + 64] = f2bf(d1 * inv * nw[lane + 64] + nb[lane + 64]);
}

// ---------------------------------------------------------------------------
// K2: fused window attention. One block (256 thr) per window.
//   w <  2048 : single pass, no channel mask, weight 1
//   w >= 2048 : 3 passes, Ca = 128/64/32, weight gumbel[p]
// Final write fuses window-reverse + roll(+3,+3) + residual: out = x + y
// LDS (63.5 KB): q/k/v/o bf16 [49][130] + union{ xt bf16[49][128], sc f32[49][49] }
// ---------------------------------------------------------------------------
__global__ __launch_bounds__(256, 2) void k_attn(
    const unsigned short* __restrict__ xw,
    const float* __restrict__ qkv_w, const float* __restrict__ qkv_b,
    const float* __restrict__ rbt,   const int*   __restrict__ rel_index,
    const float* __restrict__ attn_mask,
    const float* __restrict__ proj_w, const float* __restrict__ proj_b,
    const float* __restrict__ gw,
    const float* __restrict__ x, float* __restrict__ out) {

    __shared__ __align__(16) unsigned short s_q[49 * 130];
    __shared__ __align__(16) unsigned short s_k[49 * 130];
    __shared__ __align__(16) unsigned short s_v[49 * 130];
    __shared__ __align__(16) unsigned short s_o[49 * 130];
    __shared__ __align__(16) unsigned int   s_u[3136];   // xt (bf16[6272]) / sc (f32[2401])
    unsigned short* s_xt = (unsigned short*)s_u;
    float*          s_sc = (float*)s_u;

    const int tid = threadIdx.x;
    const int w   = blockIdx.x;
    const int bb = w >> 6, wh = (w >> 3) & 7, ww = w & 7;
    const bool sp = (w >= 2048);
    const int npass = sp ? 3 : 1;
    const unsigned short* xwin = xw + (size_t)w * 6272;

    float yacc[25];
    #pragma unroll
    for (int r = 0; r < 25; r++) yacc[r] = 0.f;

    for (int p = 0; p < npass; p++) {
        const int Ca = sp ? (128 >> p) : 128;
        const float wgt = sp ? gw[p] : 1.0f;
        __syncthreads();
        // phase 1: load (channel-masked) window tokens
        for (int idx = tid; idx < 6272; idx += 256) {
            int c = idx & 127;
            s_xt[idx] = (c < Ca) ? xwin[idx] : (unsigned short)0;
        }
        __syncthreads();
        // phase 2: qkv = x @ W^T + b   (q scaled)
        for (int idx = tid; idx < 18816; idx += 256) {
            int t = idx / 384; int o = idx - t * 384;
            const float* wr = qkv_w + o * 128;
            const unsigned short* xr = s_xt + t * 128;
            float acc = 0.f;
            for (int c = 0; c < Ca; c += 8) {
                uint4  xv = *(const uint4*)(xr + c);
                float4 w0 = *(const float4*)(wr + c);
                float4 w1 = *(const float4*)(wr + c + 4);
                float a0, a1, a2, a3, a4, a5, a6, a7;
                bfpair(xv.x, a0, a1); bfpair(xv.y, a2, a3);
                bfpair(xv.z, a4, a5); bfpair(xv.w, a6, a7);
                acc += a0 * w0.x + a1 * w0.y + a2 * w0.z + a3 * w0.w
                     + a4 * w1.x + a5 * w1.y + a6 * w1.z + a7 * w1.w;
            }
            acc += qkv_b[o];
            if (o < 128)      s_q[t * 130 + o]       = f2bf(acc * SCALE_);
            else if (o < 256) s_k[t * 130 + o - 128] = f2bf(acc);
            else              s_v[t * 130 + o - 256] = f2bf(acc);
        }
        __syncthreads();
        // phase 3: heads
        for (int h = 0; h < 4; h++) {
            // 3a: scores + rel bias + shift mask
            for (int idx = tid; idx < 2401; idx += 256) {
                int i = idx / 49; int j = idx - i * 49;
                const unsigned int* qr = (const unsigned int*)(s_q + i * 130 + h * 32);
                const unsigned int* kr = (const unsigned int*)(s_k + j * 130 + h * 32);
                float acc = 0.f;
                #pragma unroll
                for (int d = 0; d < 16; d++) {
                    float q0, q1, k0, k1;
                    bfpair(qr[d], q0, q1); bfpair(kr[d], k0, k1);
                    acc += q0 * k0 + q1 * k1;
                }
                acc += rbt[rel_index[idx] * 4 + h];
                acc += attn_mask[(w & 63) * 2401 + idx];
                s_sc[idx] = acc;
            }
            __syncthreads();
            // 3b: softmax rows (one wave per row)
            {
                int wid = tid >> 6, lane = tid & 63;
                for (int r = wid; r < 49; r += 4) {
                    float v = (lane < 49) ? s_sc[r * 49 + lane] : -3.0e38f;
                    float m = wmax(v);
                    float e = (lane < 49) ? __expf(v - m) : 0.f;
                    float ssum = wsum(e);
                    if (lane < 49) s_sc[r * 49 + lane] = e / ssum;
                }
            }
            __syncthreads();
            // 3c: o = P @ V  (pairs of d)
            for (int idx = tid; idx < 784; idx += 256) {
                int t = idx >> 4, dp = idx & 15;
                const float* pr = s_sc + t * 49;
                const unsigned int* vcol = (const unsigned int*)(s_v + h * 32 + dp * 2);
                float a0 = 0.f, a1 = 0.f;
                #pragma unroll
                for (int j = 0; j < 49; j++) {
                    float v0, v1; bfpair(vcol[j * 65], v0, v1);
                    float pv = pr[j];
                    a0 += pv * v0; a1 += pv * v1;
                }
                unsigned int packed = (unsigned int)f2bf(a0) | (((unsigned int)f2bf(a1)) << 16);
                ((unsigned int*)(s_o + t * 130 + h * 32))[dp] = packed;
            }
            __syncthreads();
        }
        // phase 4: proj (+bias), output-channel mask, gumbel weight -> register acc
        #pragma unroll
        for (int r = 0; r < 25; r++) {
            int idx = tid + 256 * r;
            if (idx < 6272) {
                int t = idx >> 7, co = idx & 127;
                if (co < Ca) {
                    const float* wr = proj_w + co * 128;
                    const unsigned int* orow = (const unsigned int*)(s_o + t * 130);
                    float acc = proj_b[co];
                    #pragma unroll 8
                    for (int c = 0; c < 32; c++) {
                        float4 wv = ((const float4*)wr)[c];
                        float a0, a1, a2, a3;
                        bfpair(orow[2 * c], a0, a1); bfpair(orow[2 * c + 1], a2, a3);
                        acc += a0 * wv.x + a1 * wv.y + a2 * wv.z + a3 * wv.w;
                    }
                    yacc[r] += wgt * acc;
                }
            }
        }
    }
    // final: window-reverse + roll(+3,+3) + residual
    #pragma unroll
    for (int r = 0; r < 25; r++) {
        int idx = tid + 256 * r;
        if (idx < 6272) {
            int t = idx >> 7, c = idx & 127;
            int i = t / 7, j = t - i * 7;
            int h2 = wh * 7 + i + SHIFT_; if (h2 >= 56) h2 -= 56;
            int w2 = ww * 7 + j + SHIFT_; if (w2 >= 56) w2 -= 56;
            size_t oidx = ((size_t)bb * 3136 + h2 * 56 + w2) * 128 + c;
            out[oidx] = x[oidx] + yacc[r];
        }
    }
}

// ---------------------------------------------------------------------------
// K4: MLP. One block per 16-token tile; S-half tiles run 3 masked passes.
// fc2 accumulators live in registers across passes; single += to d_out.
// ---------------------------------------------------------------------------
__global__ __launch_bounds__(256, 3) void k_mlp(
    const unsigned short* __restrict__ xn,
    const float* __restrict__ f1w, const float* __restrict__ f1b,
    const float* __restrict__ f2w, const float* __restrict__ f2b,
    const float* __restrict__ gw,
    float* __restrict__ out) {

    __shared__ __align__(16) float s_xT[128 * 20];  // transposed [c][t], pad 20
    __shared__ __align__(16) float s_h[16 * 516];   // hidden [t][o], pad 516

    const int tid = threadIdx.x;
    const int t0 = blockIdx.x * 16;
    const bool sp = (t0 >= 100352);
    const int npass = sp ? 3 : 1;
    const int o0 = tid, o1 = tid + 256;       // fc1 output cols
    const int co = tid & 127, tg = tid >> 7;  // fc2: out channel, token group

    float accT[8];
    #pragma unroll
    for (int i = 0; i < 8; i++) accT[i] = 0.f;

    for (int p = 0; p < npass; p++) {
        const int Ca = sp ? (128 >> p) : 128;
        const float wgt = sp ? gw[p] : 1.f;
        __syncthreads();
        // load x tile (masked), transposed
        for (int idx = tid; idx < 2048; idx += 256) {
            int t = idx >> 7, c = idx & 127;
            s_xT[c * 20 + t] = (c < Ca) ? bf2f(xn[(size_t)(t0 + t) * 128 + c]) : 0.f;
        }
        __syncthreads();
        // fc1 + exact GELU
        {
            float a0[16], a1[16];
            #pragma unroll
            for (int t = 0; t < 16; t++) { a0[t] = 0.f; a1[t] = 0.f; }
            const float* w0r = f1w + o0 * 128;
            const float* w1r = f1w + o1 * 128;
            for (int c = 0; c < Ca; c += 4) {
                float4 w0 = *(const float4*)(w0r + c);
                float4 w1 = *(const float4*)(w1r + c);
                #pragma unroll
                for (int k = 0; k < 4; k++) {
                    float wv0 = ((const float*)&w0)[k];
                    float wv1 = ((const float*)&w1)[k];
                    const float4* xc4 = (const float4*)(s_xT + (c + k) * 20);
                    float xr_[16];
                    *(float4*)(xr_ + 0)  = xc4[0];
                    *(float4*)(xr_ + 4)  = xc4[1];
                    *(float4*)(xr_ + 8)  = xc4[2];
                    *(float4*)(xr_ + 12) = xc4[3];
                    #pragma unroll
                    for (int t = 0; t < 16; t++) {
                        a0[t] += xr_[t] * wv0;
                        a1[t] += xr_[t] * wv1;
                    }
                }
            }
            float b0 = f1b[o0], b1 = f1b[o1];
            #pragma unroll
            for (int t = 0; t < 16; t++) {
                float g0 = a0[t] + b0, g1 = a1[t] + b1;
                g0 = 0.5f * g0 * (1.f + erff(g0 * 0.70710678118654752f));
                g1 = 0.5f * g1 * (1.f + erff(g1 * 0.70710678118654752f));
                s_h[t * 516 + o0] = g0;
                s_h[t * 516 + o1] = g1;
            }
        }
        __syncthreads();
        // fc2 (masked output channels), accumulate weighted into registers
        if (co < Ca) {
            const float* wr = f2w + co * 512;
            const float* hb = s_h + (tg * 8) * 516;
            float acc2[8];
            #pragma unroll
            for (int i = 0; i < 8; i++) acc2[i] = 0.f;
            for (int o = 0; o < 512; o += 4) {
                float4 wv = *(const float4*)(wr + o);
                #pragma unroll
                for (int tt = 0; tt < 8; tt++) {
                    float4 hv = *(const float4*)(hb + tt * 516 + o);
                    acc2[tt] += hv.x * wv.x + hv.y * wv.y + hv.z * wv.z + hv.w * wv.w;
                }
            }
            float bb2 = f2b[co];
            #pragma unroll
            for (int tt = 0; tt < 8; tt++) accT[tt] += wgt * (acc2[tt] + bb2);
        }
        __syncthreads();
    }
    // out += mlp  (each (t,co) owned by exactly one thread)
    #pragma unroll
    for (int tt = 0; tt < 8; tt++) {
        size_t oi = (size_t)(t0 + tg * 8 + tt) * 128 + co;
        out[oi] += accT[tt];
    }
}

// ---------------------------------------------------------------------------
extern "C" void kernel_launch(void* const* d_in, const int* in_sizes, int n_in,
                              void* d_out, int out_size, void* d_ws, size_t ws_size,
                              hipStream_t stream) {
    const float* x      = (const float*)d_in[0];
    const float* gw     = (const float*)d_in[1];
    const float* n1w    = (const float*)d_in[2];
    const float* n1b    = (const float*)d_in[3];
    const float* qkvw   = (const float*)d_in[4];
    const float* qkvb   = (const float*)d_in[5];
    const float* rbt    = (const float*)d_in[6];
    const float* pw     = (const float*)d_in[7];
    const float* pb     = (const float*)d_in[8];
    const float* amask  = (const float*)d_in[9];
    const float* n2w    = (const float*)d_in[10];
    const float* n2b    = (const float*)d_in[11];
    const float* f1w    = (const float*)d_in[12];
    const float* f1b    = (const float*)d_in[13];
    const float* f2w    = (const float*)d_in[14];
    const float* f2b    = (const float*)d_in[15];
    const int*   relidx = (const int*)d_in[16];
    float* out = (float*)d_out;

    unsigned short* xw = (unsigned short*)d_ws;            // NTOK*128 bf16 (51.4 MB)
    unsigned short* xn = xw + (size_t)NTOK * 128;          // NTOK*128 bf16 (51.4 MB)

    hipLaunchKernelGGL(k_ln1, dim3(NTOK / 4), dim3(256), 0, stream, x, n1w, n1b, xw);
    hipLaunchKernelGGL(k_attn, dim3(NWIN), dim3(256), 0, stream,
                       xw, qkvw, qkvb, rbt, relidx, amask, pw, pb, gw, x, out);
    hipLaunchKernelGGL(k_ln2, dim3(NTOK / 4), dim3(256), 0, stream, out, n2w, n2b, xn);
    hipLaunchKernelGGL(k_mlp, dim3(NTOK / 16), dim3(256), 0, stream,
                       xn, f1w, f1b, f2w, f2b, gw, out);
}

// Round 2
// 9707.509 us; speedup vs baseline: 1.1338x; 1.1338x over previous
//
#include <hip/hip_runtime.h>
#include <hip/hip_bf16.h>

// Problem constants
#define SHIFT_ 3
#define SCALE_ 0.17677669529663687f   // 32^-0.5
#define NTOK   200704                 // 64*56*56
#define NWIN   4096

typedef short v8s __attribute__((ext_vector_type(8)));
typedef float v4f __attribute__((ext_vector_type(4)));
#define MFMA16(a, b, c) __builtin_amdgcn_mfma_f32_16x16x32_bf16(a, b, c, 0, 0, 0)

static __device__ __forceinline__ unsigned short f2bf(float f) {
    union { float f; unsigned int u; } v; v.f = f;
    unsigned int u = v.u;
    unsigned int r = u + 0x7FFFu + ((u >> 16) & 1u);   // RNE
    return (unsigned short)(r >> 16);
}
static __device__ __forceinline__ float wsum(float v) {
    #pragma unroll
    for (int o = 32; o; o >>= 1) v += __shfl_xor(v, o);
    return v;
}

// ws layout (bytes):
//   0        : xw bf16 [4096 win][64 rows padded][128]   = 67,108,864  (later aliased by xn [200704][128] bf16)
//   67108864 : comb f32 [64][4][64][64]                  =  4,194,304
//   71303168 : wqkv bf16 [384][128]                      =     98,304
//   71401472 : wproj bf16 [128][128]                     =     32,768
//   71434240 : f1w bf16 [512][128]                       =    131,072
//   71565312 : f2w bf16 [128][512]                       =    131,072
#define WS_COMB  67108864
#define WS_WQKV  71303168
#define WS_WPROJ 71401472
#define WS_F1W   71434240
#define WS_F2W   71565312

// ---------------------------------------------------------------------------
// K0: prep — comb table, bf16 weight conversion, xw pad-row zeroing.
// grid covers 2,228,224 items.
// ---------------------------------------------------------------------------
__global__ __launch_bounds__(256) void k_prep(
    const float* __restrict__ amask, const float* __restrict__ rbt,
    const int* __restrict__ relidx,
    const float* __restrict__ qkvw, const float* __restrict__ projw,
    const float* __restrict__ f1w, const float* __restrict__ f2w,
    float* __restrict__ comb, unsigned short* __restrict__ wqkv,
    unsigned short* __restrict__ wproj, unsigned short* __restrict__ f1wb,
    unsigned short* __restrict__ f2wb, unsigned short* __restrict__ xw) {
    int idx = blockIdx.x * 256 + threadIdx.x;
    if (idx < 1048576) {
        int wpos = idx >> 14;
        int h = (idx >> 12) & 3;
        int i = (idx >> 6) & 63;
        int j = idx & 63;
        float v;
        if (j >= 49) v = -1e30f;
        else if (i >= 49) v = 0.f;
        else v = amask[wpos * 2401 + i * 49 + j] + rbt[relidx[i * 49 + j] * 4 + h];
        comb[idx] = v;
    } else if (idx < 1048576 + 49152) {
        int k = idx - 1048576; wqkv[k] = f2bf(qkvw[k]);
    } else if (idx < 1048576 + 49152 + 16384) {
        int k = idx - (1048576 + 49152); wproj[k] = f2bf(projw[k]);
    } else if (idx < 1048576 + 49152 + 16384 + 65536) {
        int k = idx - (1048576 + 49152 + 16384); f1wb[k] = f2bf(f1w[k]);
    } else if (idx < 1048576 + 49152 + 16384 + 65536 + 65536) {
        int k = idx - (1048576 + 49152 + 16384 + 65536); f2wb[k] = f2bf(f2w[k]);
    } else {
        int k = idx - 1245184;          // 983,040 uint4 of pad rows
        if (k < 983040) {
            int win = k / 240, r = k - win * 240;
            uint4 z = make_uint4(0u, 0u, 0u, 0u);
            *(uint4*)((char*)xw + (size_t)win * 16384 + 12544 + (size_t)r * 16) = z;
        }
    }
}

// ---------------------------------------------------------------------------
// K1: LN1 + roll(-3,-3) + window partition -> xw [win][64(pad)][128] bf16.
// ---------------------------------------------------------------------------
__global__ __launch_bounds__(256) void k_ln1(const float* __restrict__ x,
                                             const float* __restrict__ nw,
                                             const float* __restrict__ nb,
                                             unsigned short* __restrict__ xw) {
    int tok  = blockIdx.x * 4 + (threadIdx.x >> 6);
    int lane = threadIdx.x & 63;
    int win = tok / 49, t = tok - win * 49;
    int bb = win >> 6, wh = (win >> 3) & 7, ww = win & 7;
    int i = t / 7, j = t - i * 7;
    int h  = wh * 7 + i + SHIFT_; if (h  >= 56) h  -= 56;
    int w2 = ww * 7 + j + SHIFT_; if (w2 >= 56) w2 -= 56;
    const float* src = x + ((size_t)bb * 3136 + h * 56 + w2) * 128;
    float v0 = src[lane], v1 = src[lane + 64];
    float mu = wsum(v0 + v1) * (1.f / 128.f);
    float d0 = v0 - mu, d1 = v1 - mu;
    float var = wsum(d0 * d0 + d1 * d1) * (1.f / 128.f);
    float inv = rsqrtf(var + 1e-5f);
    unsigned short* dst = xw + (size_t)win * 8192 + t * 128;
    dst[lane]      = f2bf(d0 * inv * nw[lane]      + nb[lane]);
    dst[lane + 64] = f2bf(d1 * inv * nw[lane + 64] + nb[lane + 64]);
}

// ---------------------------------------------------------------------------
// K3: LN2 over x2 (= d_out after attention) -> xn bf16 [tok][128].
// ---------------------------------------------------------------------------
__global__ __launch_bounds__(256) void k_ln2(const float* __restrict__ x2,
                                             const float* __restrict__ nw,
                                             const float* __restrict__ nb,
                                             unsigned short* __restrict__ xn) {
    int tok  = blockIdx.x * 4 + (threadIdx.x >> 6);
    int lane = threadIdx.x & 63;
    const float* src = x2 + (size_t)tok * 128;
    float v0 = src[lane], v1 = src[lane + 64];
    float mu = wsum(v0 + v1) * (1.f / 128.f);
    float d0 = v0 - mu, d1 = v1 - mu;
    float var = wsum(d0 * d0 + d1 * d1) * (1.f / 128.f);
    float inv = rsqrtf(var + 1e-5f);
    unsigned short* dst = xn + (size_t)tok * 128;
    dst[lane]      = f2bf(d0 * inv * nw[lane]      + nb[lane]);
    dst[lane + 64] = f2bf(d1 * inv * nw[lane + 64] + nb[lane + 64]);
}

// ---------------------------------------------------------------------------
// K2: MFMA window attention. One block (4 waves) per window.
// LDS (62,464 B): s_q[64][136], s_k[64][136] (o reuses), vT[128][72],
//                 p per-wave [16][72].
// ---------------------------------------------------------------------------
__global__ __launch_bounds__(256, 2) void k_attn(
    const unsigned short* __restrict__ xw,
    const unsigned short* __restrict__ wqkv, const float* __restrict__ qkvb,
    const float* __restrict__ comb,
    const unsigned short* __restrict__ wproj, const float* __restrict__ pbias,
    const float* __restrict__ gw,
    const float* __restrict__ x, float* __restrict__ out) {

    __shared__ unsigned short sm[31232];
    unsigned short* s_q = sm;            // [64][136]
    unsigned short* s_k = sm + 8704;     // [64][136], later o
    unsigned short* s_v = sm + 17408;    // vT [128][72]
    unsigned short* s_p = sm + 26624;    // 4 x [16][72]

    const int tid = threadIdx.x, wv = tid >> 6, lane = tid & 63;
    const int li = lane & 15, lg = lane >> 4;
    const int w = blockIdx.x;
    const int wpos = w & 63;
    const bool sp = (w >= 2048);
    const int npass = sp ? 3 : 1;
    const unsigned short* xwin = xw + (size_t)w * 8192;
    unsigned short* pw_ = s_p + wv * 1152;

    const v4f z4 = {0.f, 0.f, 0.f, 0.f};
    v4f yacc[2][4];
    #pragma unroll
    for (int n = 0; n < 2; n++)
        #pragma unroll
        for (int m = 0; m < 4; m++) yacc[n][m] = z4;

    for (int p = 0; p < npass; p++) {
        const int Ka = sp ? (4 >> p) : 4;
        const int Ca = sp ? (128 >> p) : 128;
        const float wgt = sp ? gw[p] : 1.0f;

        // ---- QKV (n-split): wave handles cols [wv*96, wv*96+96) of 384 ----
        v8s ax[4][4];
        for (int m = 0; m < 4; m++)
            for (int k = 0; k < Ka; k++)
                ax[m][k] = *(const v8s*)(xwin + (m * 16 + li) * 128 + k * 32 + lg * 8);
        for (int nt = 0; nt < 6; nt++) {
            int ntg = wv * 6 + nt, o0 = ntg * 16;
            v4f acc[4] = {z4, z4, z4, z4};
            for (int k = 0; k < Ka; k++) {
                v8s b = *(const v8s*)(wqkv + (o0 + li) * 128 + k * 32 + lg * 8);
                #pragma unroll
                for (int m = 0; m < 4; m++) acc[m] = MFMA16(ax[m][k], b, acc[m]);
            }
            float bo = qkvb[o0 + li];
            if (ntg < 16) {              // q or k, token-major [64][136]
                unsigned short* dst = (ntg < 8) ? s_q : s_k;
                int oc = (ntg < 8) ? o0 : o0 - 128;
                float scl = (ntg < 8) ? SCALE_ : 1.f;
                #pragma unroll
                for (int m = 0; m < 4; m++)
                    #pragma unroll
                    for (int r = 0; r < 4; r++)
                        dst[(m * 16 + lg * 4 + r) * 136 + oc + li] =
                            f2bf((acc[m][r] + bo) * scl);
            } else {                     // v transposed: vT[d][t], [128][72]
                int d = (ntg - 16) * 16 + li;
                #pragma unroll
                for (int m = 0; m < 4; m++) {
                    int t0_ = m * 16 + lg * 4;
                    unsigned int p0 = (unsigned int)f2bf(acc[m][0] + bo) |
                                      ((unsigned int)f2bf(acc[m][1] + bo) << 16);
                    unsigned int p1 = (unsigned int)f2bf(acc[m][2] + bo) |
                                      ((unsigned int)f2bf(acc[m][3] + bo) << 16);
                    *(unsigned int*)(s_v + d * 72 + t0_)     = p0;
                    *(unsigned int*)(s_v + d * 72 + t0_ + 2) = p1;
                }
            }
        }
        __syncthreads();   // s1: q,k,vT visible

        // ---- heads (m-split): wave owns query rows [wv*16, wv*16+16) ----
        v4f oacc[8];
        #pragma unroll
        for (int i = 0; i < 8; i++) oacc[i] = z4;
        for (int h = 0; h < 4; h++) {
            v8s aq = *(const v8s*)(s_q + (wv * 16 + li) * 136 + h * 32 + lg * 8);
            v4f sc[4];
            #pragma unroll
            for (int ntj = 0; ntj < 4; ntj++) {
                v8s bk = *(const v8s*)(s_k + (ntj * 16 + li) * 136 + h * 32 + lg * 8);
                sc[ntj] = MFMA16(aq, bk, z4);
            }
            const float* cb = comb + ((size_t)(wpos * 4 + h) << 12) + (wv * 16 + lg * 4) * 64;
            #pragma unroll
            for (int r = 0; r < 4; r++) {
                float vmax = -3.0e38f, e[4];
                #pragma unroll
                for (int ntj = 0; ntj < 4; ntj++) {
                    float v_ = sc[ntj][r] + cb[r * 64 + ntj * 16 + li];
                    sc[ntj][r] = v_;
                    vmax = fmaxf(vmax, v_);
                }
                #pragma unroll
                for (int o_ = 1; o_ < 16; o_ <<= 1) vmax = fmaxf(vmax, __shfl_xor(vmax, o_));
                float ssum = 0.f;
                #pragma unroll
                for (int ntj = 0; ntj < 4; ntj++) {
                    e[ntj] = __expf(sc[ntj][r] - vmax);
                    ssum += e[ntj];
                }
                #pragma unroll
                for (int o_ = 1; o_ < 16; o_ <<= 1) ssum += __shfl_xor(ssum, o_);
                float inv = __builtin_amdgcn_rcpf(ssum);
                #pragma unroll
                for (int ntj = 0; ntj < 4; ntj++)
                    pw_[(lg * 4 + r) * 72 + ntj * 16 + li] = f2bf(e[ntj] * inv);
            }
            // PV: O[t][h*32+d] += P @ V
            #pragma unroll
            for (int k0 = 0; k0 < 2; k0++) {
                v8s ap = *(const v8s*)(pw_ + li * 72 + k0 * 32 + lg * 8);
                #pragma unroll
                for (int dn = 0; dn < 2; dn++) {
                    v8s bv = *(const v8s*)(s_v + (h * 32 + dn * 16 + li) * 72 + k0 * 32 + lg * 8);
                    oacc[h * 2 + dn] = MFMA16(ap, bv, oacc[h * 2 + dn]);
                }
            }
        }
        __syncthreads();   // s2: all waves done reading s_k/s_vT/s_q

        // ---- o -> LDS (reuse s_k region), token-major [64][136] ----
        unsigned short* s_o = s_k;
        #pragma unroll
        for (int ot = 0; ot < 8; ot++)
            #pragma unroll
            for (int r = 0; r < 4; r++)
                s_o[(wv * 16 + lg * 4 + r) * 136 + ot * 16 + li] = f2bf(oacc[ot][r]);
        __syncthreads();   // s3: o visible

        // ---- proj (n-split, interleaved tiles (nt*4+wv)*16, tile-masked) ----
        if (wv * 16 < Ca) {
            v8s ao[4][4];
            for (int m = 0; m < 4; m++)
                #pragma unroll
                for (int k = 0; k < 4; k++)
                    ao[m][k] = *(const v8s*)(s_o + (m * 16 + li) * 136 + k * 32 + lg * 8);
            #pragma unroll
            for (int nt = 0; nt < 2; nt++) {
                int co0 = (nt * 4 + wv) * 16;
                if (co0 < Ca) {
                    v4f pacc[4] = {z4, z4, z4, z4};
                    #pragma unroll
                    for (int k = 0; k < 4; k++) {
                        v8s b = *(const v8s*)(wproj + (co0 + li) * 128 + k * 32 + lg * 8);
                        #pragma unroll
                        for (int m = 0; m < 4; m++) pacc[m] = MFMA16(ao[m][k], b, pacc[m]);
                    }
                    float bo = pbias[co0 + li];
                    #pragma unroll
                    for (int m = 0; m < 4; m++)
                        #pragma unroll
                        for (int r = 0; r < 4; r++)
                            yacc[nt][m][r] += wgt * (pacc[m][r] + bo);
                }
            }
        }
        __syncthreads();   // s4: end of pass
    }

    // ---- epilogue: window-reverse + roll(+3,+3) + residual ----
    const int bb = w >> 6, wh = (w >> 3) & 7, ww = w & 7;
    for (int m = 0; m < 4; m++)
        #pragma unroll
        for (int r = 0; r < 4; r++) {
            int t = m * 16 + lg * 4 + r;
            if (t < 49) {
                int ti = t / 7, tj = t - ti * 7;
                int h2 = wh * 7 + ti + SHIFT_; if (h2 >= 56) h2 -= 56;
                int w2 = ww * 7 + tj + SHIFT_; if (w2 >= 56) w2 -= 56;
                size_t base = ((size_t)bb * 3136 + h2 * 56 + w2) * 128;
                #pragma unroll
                for (int nt = 0; nt < 2; nt++) {
                    int c = (nt * 4 + wv) * 16 + li;
                    out[base + c] = x[base + c] + yacc[nt][m][r];
                }
            }
        }
}

// ---------------------------------------------------------------------------
// K4: MFMA MLP. One block (4 waves) per 32 tokens. S-half: 3 masked passes.
// ---------------------------------------------------------------------------
__global__ __launch_bounds__(256, 3) void k_mlp(
    const unsigned short* __restrict__ xn,
    const unsigned short* __restrict__ f1wb, const float* __restrict__ f1b,
    const unsigned short* __restrict__ f2wb, const float* __restrict__ f2b,
    const float* __restrict__ gw, float* __restrict__ out) {

    __shared__ unsigned short s_h[32 * 520];   // hidden bf16 [32][520]

    const int tid = threadIdx.x, wv = tid >> 6, lane = tid & 63;
    const int li = lane & 15, lg = lane >> 4;
    const int t0 = blockIdx.x * 32;
    const bool sp = (t0 >= 100352);
    const int npass = sp ? 3 : 1;

    const v4f z4 = {0.f, 0.f, 0.f, 0.f};
    v4f yacc[2][2];
    #pragma unroll
    for (int n = 0; n < 2; n++)
        #pragma unroll
        for (int m = 0; m < 2; m++) yacc[n][m] = z4;

    for (int p = 0; p < npass; p++) {
        const int Ka = sp ? (4 >> p) : 4;
        const int Ca = sp ? (128 >> p) : 128;
        const float wgt = sp ? gw[p] : 1.f;
        if (p) __syncthreads();          // protect s_h vs previous fc2 reads

        // fc1 (n-split: wave cols [wv*128, wv*128+128)) + exact GELU
        v8s ax[2][4];
        for (int m = 0; m < 2; m++)
            for (int k = 0; k < Ka; k++)
                ax[m][k] = *(const v8s*)(xn + (size_t)(t0 + m * 16 + li) * 128 + k * 32 + lg * 8);
        for (int nt = 0; nt < 8; nt++) {
            int o0 = wv * 128 + nt * 16;
            v4f acc[2] = {z4, z4};
            for (int k = 0; k < Ka; k++) {
                v8s b = *(const v8s*)(f1wb + (o0 + li) * 128 + k * 32 + lg * 8);
                #pragma unroll
                for (int m = 0; m < 2; m++) acc[m] = MFMA16(ax[m][k], b, acc[m]);
            }
            float bo = f1b[o0 + li];
            #pragma unroll
            for (int m = 0; m < 2; m++)
                #pragma unroll
                for (int r = 0; r < 4; r++) {
                    float v_ = acc[m][r] + bo;
                    v_ = 0.5f * v_ * (1.f + erff(v_ * 0.70710678118654752f));
                    s_h[(m * 16 + lg * 4 + r) * 520 + o0 + li] = f2bf(v_);
                }
        }
        __syncthreads();

        // fc2: interleaved output tiles (nt*4+wv)*16, tile-masked, K=512
        int co0_0 = wv * 16, co0_1 = (4 + wv) * 16;
        bool act0 = co0_0 < Ca, act1 = co0_1 < Ca;
        v4f acc2[2][2] = {{z4, z4}, {z4, z4}};
        for (int k = 0; k < 16; k++) {
            v8s a0 = *(const v8s*)(s_h + (li) * 520 + k * 32 + lg * 8);
            v8s a1 = *(const v8s*)(s_h + (16 + li) * 520 + k * 32 + lg * 8);
            if (act0) {
                v8s b = *(const v8s*)(f2wb + (co0_0 + li) * 512 + k * 32 + lg * 8);
                acc2[0][0] = MFMA16(a0, b, acc2[0][0]);
                acc2[0][1] = MFMA16(a1, b, acc2[0][1]);
            }
            if (act1) {
                v8s b = *(const v8s*)(f2wb + (co0_1 + li) * 512 + k * 32 + lg * 8);
                acc2[1][0] = MFMA16(a0, b, acc2[1][0]);
                acc2[1][1] = MFMA16(a1, b, acc2[1][1]);
            }
        }
        if (act0) {
            float bo = f2b[co0_0 + li];
            #pragma unroll
            for (int m = 0; m < 2; m++)
                #pragma unroll
                for (int r = 0; r < 4; r++) yacc[0][m][r] += wgt * (acc2[0][m][r] + bo);
        }
        if (act1) {
            float bo = f2b[co0_1 + li];
            #pragma unroll
            for (int m = 0; m < 2; m++)
                #pragma unroll
                for (int r = 0; r < 4; r++) yacc[1][m][r] += wgt * (acc2[1][m][r] + bo);
        }
    }

    // epilogue: out += mlp
    #pragma unroll
    for (int nt = 0; nt < 2; nt++) {
        int co = (nt * 4 + wv) * 16 + li;
        #pragma unroll
        for (int m = 0; m < 2; m++)
            #pragma unroll
            for (int r = 0; r < 4; r++) {
                size_t oi = (size_t)(t0 + m * 16 + lg * 4 + r) * 128 + co;
                out[oi] += yacc[nt][m][r];
            }
    }
}

// ---------------------------------------------------------------------------
extern "C" void kernel_launch(void* const* d_in, const int* in_sizes, int n_in,
                              void* d_out, int out_size, void* d_ws, size_t ws_size,
                              hipStream_t stream) {
    const float* x      = (const float*)d_in[0];
    const float* gw     = (const float*)d_in[1];
    const float* n1w    = (const float*)d_in[2];
    const float* n1b    = (const float*)d_in[3];
    const float* qkvw   = (const float*)d_in[4];
    const float* qkvb   = (const float*)d_in[5];
    const float* rbt    = (const float*)d_in[6];
    const float* pw     = (const float*)d_in[7];
    const float* pb     = (const float*)d_in[8];
    const float* amask  = (const float*)d_in[9];
    const float* n2w    = (const float*)d_in[10];
    const float* n2b    = (const float*)d_in[11];
    const float* f1w    = (const float*)d_in[12];
    const float* f1b    = (const float*)d_in[13];
    const float* f2w    = (const float*)d_in[14];
    const float* f2b    = (const float*)d_in[15];
    const int*   relidx = (const int*)d_in[16];
    float* out = (float*)d_out;

    unsigned short* xw    = (unsigned short*)d_ws;
    float*          comb  = (float*)((char*)d_ws + WS_COMB);
    unsigned short* wqkv  = (unsigned short*)((char*)d_ws + WS_WQKV);
    unsigned short* wproj = (unsigned short*)((char*)d_ws + WS_WPROJ);
    unsigned short* f1wb  = (unsigned short*)((char*)d_ws + WS_F1W);
    unsigned short* f2wb  = (unsigned short*)((char*)d_ws + WS_F2W);
    unsigned short* xn    = (unsigned short*)d_ws;   // aliases xw (dead by then)

    hipLaunchKernelGGL(k_prep, dim3(8704), dim3(256), 0, stream,
                       amask, rbt, relidx, qkvw, pw, f1w, f2w,
                       comb, wqkv, wproj, f1wb, f2wb, xw);
    hipLaunchKernelGGL(k_ln1, dim3(NTOK / 4), dim3(256), 0, stream, x, n1w, n1b, xw);
    hipLaunchKernelGGL(k_attn, dim3(NWIN), dim3(256), 0, stream,
                       xw, wqkv, qkvb, comb, wproj, pb, gw, x, out);
    hipLaunchKernelGGL(k_ln2, dim3(NTOK / 4), dim3(256), 0, stream, out, n2w, n2b, xn);
    hipLaunchKernelGGL(k_mlp, dim3(NTOK / 32), dim3(256), 0, stream,
                       xn, f1wb, f1b, f2wb, f2b, gw, out);
}

// Round 3
// 853.085 us; speedup vs baseline: 12.9015x; 11.3793x over previous
//
#include <hip/hip_runtime.h>
#include <hip/hip_bf16.h>

// Problem constants
#define SHIFT_ 3
#define SCALE_ 0.17677669529663687f   // 32^-0.5
#define NTOK   200704                 // 64*56*56
#define NWIN   4096

typedef short v8s __attribute__((ext_vector_type(8)));
typedef float v4f __attribute__((ext_vector_type(4)));
#define MFMA16(a, b, c) __builtin_amdgcn_mfma_f32_16x16x32_bf16(a, b, c, 0, 0, 0)

static __device__ __forceinline__ unsigned short f2bf(float f) {
    union { float f; unsigned int u; } v; v.f = f;
    unsigned int u = v.u;
    unsigned int r = u + 0x7FFFu + ((u >> 16) & 1u);   // RNE
    return (unsigned short)(r >> 16);
}
static __device__ __forceinline__ float wsum(float v) {
    #pragma unroll
    for (int o = 32; o; o >>= 1) v += __shfl_xor(v, o);
    return v;
}

// ws layout (bytes):
//   0        : xw bf16 [4096 win][64 rows padded][128]   (later aliased by xn)
//   67108864 : comb f32 [64][4][64][64]
//   71303168 : wqkv bf16 [384][128]
//   71401472 : wproj bf16 [128][128]
//   71434240 : f1w bf16 [512][128]
//   71565312 : f2w bf16 [128][512]
#define WS_COMB  67108864
#define WS_WQKV  71303168
#define WS_WPROJ 71401472
#define WS_F1W   71434240
#define WS_F2W   71565312

// ---------------------------------------------------------------------------
// K0: prep — comb table, bf16 weight conversion, xw pad-row zeroing.
// ---------------------------------------------------------------------------
__global__ __launch_bounds__(256) void k_prep(
    const float* __restrict__ amask, const float* __restrict__ rbt,
    const int* __restrict__ relidx,
    const float* __restrict__ qkvw, const float* __restrict__ projw,
    const float* __restrict__ f1w, const float* __restrict__ f2w,
    float* __restrict__ comb, unsigned short* __restrict__ wqkv,
    unsigned short* __restrict__ wproj, unsigned short* __restrict__ f1wb,
    unsigned short* __restrict__ f2wb, unsigned short* __restrict__ xw) {
    int idx = blockIdx.x * 256 + threadIdx.x;
    if (idx < 1048576) {
        int wpos = idx >> 14;
        int h = (idx >> 12) & 3;
        int i = (idx >> 6) & 63;
        int j = idx & 63;
        float v;
        if (j >= 49) v = -1e30f;
        else if (i >= 49) v = 0.f;
        else v = amask[wpos * 2401 + i * 49 + j] + rbt[relidx[i * 49 + j] * 4 + h];
        comb[idx] = v;
    } else if (idx < 1048576 + 49152) {
        int k = idx - 1048576; wqkv[k] = f2bf(qkvw[k]);
    } else if (idx < 1048576 + 49152 + 16384) {
        int k = idx - (1048576 + 49152); wproj[k] = f2bf(projw[k]);
    } else if (idx < 1048576 + 49152 + 16384 + 65536) {
        int k = idx - (1048576 + 49152 + 16384); f1wb[k] = f2bf(f1w[k]);
    } else if (idx < 1048576 + 49152 + 16384 + 65536 + 65536) {
        int k = idx - (1048576 + 49152 + 16384 + 65536); f2wb[k] = f2bf(f2w[k]);
    } else {
        int k = idx - 1245184;          // 983,040 uint4 of pad rows
        if (k < 983040) {
            int win = k / 240, r = k - win * 240;
            uint4 z = make_uint4(0u, 0u, 0u, 0u);
            *(uint4*)((char*)xw + (size_t)win * 16384 + 12544 + (size_t)r * 16) = z;
        }
    }
}

// ---------------------------------------------------------------------------
// K1: LN1 + roll(-3,-3) + window partition -> xw [win][64(pad)][128] bf16.
// ---------------------------------------------------------------------------
__global__ __launch_bounds__(256) void k_ln1(const float* __restrict__ x,
                                             const float* __restrict__ nw,
                                             const float* __restrict__ nb,
                                             unsigned short* __restrict__ xw) {
    int tok  = blockIdx.x * 4 + (threadIdx.x >> 6);
    int lane = threadIdx.x & 63;
    int win = tok / 49, t = tok - win * 49;
    int bb = win >> 6, wh = (win >> 3) & 7, ww = win & 7;
    int i = t / 7, j = t - i * 7;
    int h  = wh * 7 + i + SHIFT_; if (h  >= 56) h  -= 56;
    int w2 = ww * 7 + j + SHIFT_; if (w2 >= 56) w2 -= 56;
    const float* src = x + ((size_t)bb * 3136 + h * 56 + w2) * 128;
    float v0 = src[lane], v1 = src[lane + 64];
    float mu = wsum(v0 + v1) * (1.f / 128.f);
    float d0 = v0 - mu, d1 = v1 - mu;
    float var = wsum(d0 * d0 + d1 * d1) * (1.f / 128.f);
    float inv = rsqrtf(var + 1e-5f);
    unsigned short* dst = xw + (size_t)win * 8192 + t * 128;
    dst[lane]      = f2bf(d0 * inv * nw[lane]      + nb[lane]);
    dst[lane + 64] = f2bf(d1 * inv * nw[lane + 64] + nb[lane + 64]);
}

// ---------------------------------------------------------------------------
// K3: LN2 over x2 (= d_out after attention) -> xn bf16 [tok][128].
// ---------------------------------------------------------------------------
__global__ __launch_bounds__(256) void k_ln2(const float* __restrict__ x2,
                                             const float* __restrict__ nw,
                                             const float* __restrict__ nb,
                                             unsigned short* __restrict__ xn) {
    int tok  = blockIdx.x * 4 + (threadIdx.x >> 6);
    int lane = threadIdx.x & 63;
    const float* src = x2 + (size_t)tok * 128;
    float v0 = src[lane], v1 = src[lane + 64];
    float mu = wsum(v0 + v1) * (1.f / 128.f);
    float d0 = v0 - mu, d1 = v1 - mu;
    float var = wsum(d0 * d0 + d1 * d1) * (1.f / 128.f);
    float inv = rsqrtf(var + 1e-5f);
    unsigned short* dst = xn + (size_t)tok * 128;
    dst[lane]      = f2bf(d0 * inv * nw[lane]      + nb[lane]);
    dst[lane + 64] = f2bf(d1 * inv * nw[lane + 64] + nb[lane + 64]);
}

// ---------------------------------------------------------------------------
// K2: MFMA window attention, pass body templated on KA (K-chunks = KA, Ca=32*KA).
// ---------------------------------------------------------------------------
template<int KA>
__device__ __forceinline__ void attn_pass(
    const v8s (&ax)[4][4],
    const unsigned short* __restrict__ wqkv, const float* __restrict__ qkvb,
    const float* __restrict__ comb,
    const unsigned short* __restrict__ wproj, const float* __restrict__ pbias,
    float wgt, int wpos, int wv, int li, int lg,
    unsigned short* __restrict__ s_q, unsigned short* __restrict__ s_k,
    unsigned short* __restrict__ s_v, unsigned short* __restrict__ pw_,
    v4f (&yacc)[2][4])
{
    const v4f z4 = {0.f, 0.f, 0.f, 0.f};
    constexpr int Ca = KA * 32;

    // ---- QKV (n-split): wave handles cols [wv*96, wv*96+96) of 384 ----
    #pragma unroll 2
    for (int nt = 0; nt < 6; nt++) {
        const int ntg = wv * 6 + nt, o0 = ntg * 16;
        v4f acc[4] = {z4, z4, z4, z4};
        #pragma unroll
        for (int k = 0; k < KA; k++) {
            v8s b = *(const v8s*)(wqkv + (o0 + li) * 128 + k * 32 + lg * 8);
            #pragma unroll
            for (int m = 0; m < 4; m++) acc[m] = MFMA16(ax[m][k], b, acc[m]);
        }
        float bo = qkvb[o0 + li];
        if (ntg < 16) {              // q or k, token-major [64][136]
            unsigned short* dst = (ntg < 8) ? s_q : s_k;
            const int oc = (ntg < 8) ? o0 : o0 - 128;
            const float scl = (ntg < 8) ? SCALE_ : 1.f;
            #pragma unroll
            for (int m = 0; m < 4; m++)
                #pragma unroll
                for (int r = 0; r < 4; r++)
                    dst[(m * 16 + lg * 4 + r) * 136 + oc + li] =
                        f2bf((acc[m][r] + bo) * scl);
        } else {                     // v transposed: vT[d][t], [128][72]
            const int d = (ntg - 16) * 16 + li;
            #pragma unroll
            for (int m = 0; m < 4; m++) {
                int t0_ = m * 16 + lg * 4;
                unsigned int p0 = (unsigned int)f2bf(acc[m][0] + bo) |
                                  ((unsigned int)f2bf(acc[m][1] + bo) << 16);
                unsigned int p1 = (unsigned int)f2bf(acc[m][2] + bo) |
                                  ((unsigned int)f2bf(acc[m][3] + bo) << 16);
                *(unsigned int*)(s_v + d * 72 + t0_)     = p0;
                *(unsigned int*)(s_v + d * 72 + t0_ + 2) = p1;
            }
        }
    }
    __syncthreads();   // s1: q,k,vT visible

    // ---- heads (m-split): wave owns query rows [wv*16, wv*16+16) ----
    v4f oacc[8];
    #pragma unroll
    for (int i = 0; i < 8; i++) oacc[i] = z4;
    #pragma unroll 2
    for (int h = 0; h < 4; h++) {
        v8s aq = *(const v8s*)(s_q + (wv * 16 + li) * 136 + h * 32 + lg * 8);
        v4f sc[4];
        #pragma unroll
        for (int ntj = 0; ntj < 4; ntj++) {
            v8s bk = *(const v8s*)(s_k + (ntj * 16 + li) * 136 + h * 32 + lg * 8);
            sc[ntj] = MFMA16(aq, bk, z4);
        }
        const float* cb = comb + ((size_t)(wpos * 4 + h) << 12) + (wv * 16 + lg * 4) * 64;
        #pragma unroll
        for (int r = 0; r < 4; r++) {
            float vmax = -3.0e38f, e[4];
            #pragma unroll
            for (int ntj = 0; ntj < 4; ntj++) {
                float v_ = sc[ntj][r] + cb[r * 64 + ntj * 16 + li];
                sc[ntj][r] = v_;
                vmax = fmaxf(vmax, v_);
            }
            #pragma unroll
            for (int o_ = 1; o_ < 16; o_ <<= 1) vmax = fmaxf(vmax, __shfl_xor(vmax, o_));
            float ssum = 0.f;
            #pragma unroll
            for (int ntj = 0; ntj < 4; ntj++) {
                e[ntj] = __expf(sc[ntj][r] - vmax);
                ssum += e[ntj];
            }
            #pragma unroll
            for (int o_ = 1; o_ < 16; o_ <<= 1) ssum += __shfl_xor(ssum, o_);
            float inv = __builtin_amdgcn_rcpf(ssum);
            #pragma unroll
            for (int ntj = 0; ntj < 4; ntj++)
                pw_[(lg * 4 + r) * 72 + ntj * 16 + li] = f2bf(e[ntj] * inv);
        }
        // PV: O[t][h*32+d] += P @ V
        #pragma unroll
        for (int k0 = 0; k0 < 2; k0++) {
            v8s ap = *(const v8s*)(pw_ + li * 72 + k0 * 32 + lg * 8);
            #pragma unroll
            for (int dn = 0; dn < 2; dn++) {
                v8s bv = *(const v8s*)(s_v + (h * 32 + dn * 16 + li) * 72 + k0 * 32 + lg * 8);
                oacc[h * 2 + dn] = MFMA16(ap, bv, oacc[h * 2 + dn]);
            }
        }
    }
    __syncthreads();   // s2: all waves done reading s_k/s_v/s_q

    // ---- o -> LDS (reuse s_k region), token-major [64][136] ----
    unsigned short* s_o = s_k;
    #pragma unroll
    for (int ot = 0; ot < 8; ot++)
        #pragma unroll
        for (int r = 0; r < 4; r++)
            s_o[(wv * 16 + lg * 4 + r) * 136 + ot * 16 + li] = f2bf(oacc[ot][r]);
    __syncthreads();   // s3: o visible

    // ---- proj (n-split, interleaved tiles (nt*4+wv)*16, compile-time mask) ----
    if (KA == 4 || wv * 16 < Ca) {
        v8s ao[4][4];
        #pragma unroll
        for (int m = 0; m < 4; m++)
            #pragma unroll
            for (int k = 0; k < 4; k++)
                ao[m][k] = *(const v8s*)(s_o + (m * 16 + li) * 136 + k * 32 + lg * 8);
        #pragma unroll
        for (int nt = 0; nt < 2; nt++) {
            const int co0 = (nt * 4 + wv) * 16;
            if (nt == 0 || Ca == 128) {
                if (co0 < Ca) {
                    v4f pacc[4] = {z4, z4, z4, z4};
                    #pragma unroll
                    for (int k = 0; k < 4; k++) {
                        v8s b = *(const v8s*)(wproj + (co0 + li) * 128 + k * 32 + lg * 8);
                        #pragma unroll
                        for (int m = 0; m < 4; m++) pacc[m] = MFMA16(ao[m][k], b, pacc[m]);
                    }
                    float bo = pbias[co0 + li];
                    #pragma unroll
                    for (int m = 0; m < 4; m++)
                        #pragma unroll
                        for (int r = 0; r < 4; r++)
                            yacc[nt][m][r] += wgt * (pacc[m][r] + bo);
                }
            }
        }
    }
    __syncthreads();   // s4: end of pass (protects s_q/s_k/s_v reuse)
}

__global__ __launch_bounds__(256, 2) void k_attn(
    const unsigned short* __restrict__ xw,
    const unsigned short* __restrict__ wqkv, const float* __restrict__ qkvb,
    const float* __restrict__ comb,
    const unsigned short* __restrict__ wproj, const float* __restrict__ pbias,
    const float* __restrict__ gw,
    const float* __restrict__ x, float* __restrict__ out) {

    __shared__ unsigned short sm[31232];
    unsigned short* s_q = sm;            // [64][136]
    unsigned short* s_k = sm + 8704;     // [64][136], later o
    unsigned short* s_v = sm + 17408;    // vT [128][72]
    unsigned short* s_p = sm + 26624;    // 4 x [16][72]

    const int tid = threadIdx.x, wv = tid >> 6, lane = tid & 63;
    const int li = lane & 15, lg = lane >> 4;
    const int w = blockIdx.x;
    const int wpos = w & 63;
    const bool sp = (w >= 2048);
    const unsigned short* xwin = xw + (size_t)w * 8192;
    unsigned short* pw_ = s_p + wv * 1152;

    const v4f z4 = {0.f, 0.f, 0.f, 0.f};
    v4f yacc[2][4];
    #pragma unroll
    for (int n = 0; n < 2; n++)
        #pragma unroll
        for (int m = 0; m < 4; m++) yacc[n][m] = z4;

    // A-fragments of x (pass-invariant): load once
    v8s ax[4][4];
    #pragma unroll
    for (int m = 0; m < 4; m++)
        #pragma unroll
        for (int k = 0; k < 4; k++)
            ax[m][k] = *(const v8s*)(xwin + (m * 16 + li) * 128 + k * 32 + lg * 8);

    if (sp) {
        attn_pass<4>(ax, wqkv, qkvb, comb, wproj, pbias, gw[0], wpos, wv, li, lg,
                     s_q, s_k, s_v, pw_, yacc);
        attn_pass<2>(ax, wqkv, qkvb, comb, wproj, pbias, gw[1], wpos, wv, li, lg,
                     s_q, s_k, s_v, pw_, yacc);
        attn_pass<1>(ax, wqkv, qkvb, comb, wproj, pbias, gw[2], wpos, wv, li, lg,
                     s_q, s_k, s_v, pw_, yacc);
    } else {
        attn_pass<4>(ax, wqkv, qkvb, comb, wproj, pbias, 1.f, wpos, wv, li, lg,
                     s_q, s_k, s_v, pw_, yacc);
    }

    // ---- epilogue: window-reverse + roll(+3,+3) + residual ----
    const int bb = w >> 6, wh = (w >> 3) & 7, ww = w & 7;
    #pragma unroll
    for (int m = 0; m < 4; m++)
        #pragma unroll
        for (int r = 0; r < 4; r++) {
            int t = m * 16 + lg * 4 + r;
            if (t < 49) {
                int ti = t / 7, tj = t - ti * 7;
                int h2 = wh * 7 + ti + SHIFT_; if (h2 >= 56) h2 -= 56;
                int w2 = ww * 7 + tj + SHIFT_; if (w2 >= 56) w2 -= 56;
                size_t base = ((size_t)bb * 3136 + h2 * 56 + w2) * 128;
                #pragma unroll
                for (int nt = 0; nt < 2; nt++) {
                    int c = (nt * 4 + wv) * 16 + li;
                    out[base + c] = x[base + c] + yacc[nt][m][r];
                }
            }
        }
}

// ---------------------------------------------------------------------------
// K4: MFMA MLP, pass body templated on KA. One block (4 waves) per 32 tokens.
// ---------------------------------------------------------------------------
template<int KA>
__device__ __forceinline__ void mlp_pass(
    const v8s (&ax)[2][4],
    const unsigned short* __restrict__ f1wb, const float* __restrict__ f1b,
    const unsigned short* __restrict__ f2wb, const float* __restrict__ f2b,
    float wgt, int wv, int li, int lg,
    unsigned short* __restrict__ s_h, v4f (&yacc)[2][2])
{
    const v4f z4 = {0.f, 0.f, 0.f, 0.f};
    constexpr int Ca = KA * 32;

    // fc1 (n-split: wave cols [wv*128, wv*128+128)) + exact GELU -> s_h bf16
    #pragma unroll 4
    for (int nt = 0; nt < 8; nt++) {
        const int o0 = wv * 128 + nt * 16;
        v4f acc[2] = {z4, z4};
        #pragma unroll
        for (int k = 0; k < KA; k++) {
            v8s b = *(const v8s*)(f1wb + (o0 + li) * 128 + k * 32 + lg * 8);
            acc[0] = MFMA16(ax[0][k], b, acc[0]);
            acc[1] = MFMA16(ax[1][k], b, acc[1]);
        }
        float bo = f1b[o0 + li];
        #pragma unroll
        for (int m = 0; m < 2; m++)
            #pragma unroll
            for (int r = 0; r < 4; r++) {
                float v_ = acc[m][r] + bo;
                v_ = 0.5f * v_ * (1.f + erff(v_ * 0.70710678118654752f));
                s_h[(m * 16 + lg * 4 + r) * 520 + o0 + li] = f2bf(v_);
            }
    }
    __syncthreads();

    // fc2: tiles co0 = wv*16 and 64+wv*16, compile-time masked, K=512 unrolled
    if (KA == 4) {
        const int c0 = wv * 16, c1 = 64 + wv * 16;
        v4f acc2[2][2] = {{z4, z4}, {z4, z4}};
        #pragma unroll
        for (int k = 0; k < 16; k++) {
            v8s a0 = *(const v8s*)(s_h + li * 520 + k * 32 + lg * 8);
            v8s a1 = *(const v8s*)(s_h + (16 + li) * 520 + k * 32 + lg * 8);
            v8s b0 = *(const v8s*)(f2wb + (c0 + li) * 512 + k * 32 + lg * 8);
            v8s b1 = *(const v8s*)(f2wb + (c1 + li) * 512 + k * 32 + lg * 8);
            acc2[0][0] = MFMA16(a0, b0, acc2[0][0]);
            acc2[0][1] = MFMA16(a1, b0, acc2[0][1]);
            acc2[1][0] = MFMA16(a0, b1, acc2[1][0]);
            acc2[1][1] = MFMA16(a1, b1, acc2[1][1]);
        }
        float bo0 = f2b[c0 + li], bo1 = f2b[c1 + li];
        #pragma unroll
        for (int m = 0; m < 2; m++)
            #pragma unroll
            for (int r = 0; r < 4; r++) {
                yacc[0][m][r] += wgt * (acc2[0][m][r] + bo0);
                yacc[1][m][r] += wgt * (acc2[1][m][r] + bo1);
            }
    } else if (KA == 2 || wv < 2) {
        const int c0 = wv * 16;         // < Ca guaranteed
        v4f acc2[2] = {z4, z4};
        #pragma unroll
        for (int k = 0; k < 16; k++) {
            v8s a0 = *(const v8s*)(s_h + li * 520 + k * 32 + lg * 8);
            v8s a1 = *(const v8s*)(s_h + (16 + li) * 520 + k * 32 + lg * 8);
            v8s b0 = *(const v8s*)(f2wb + (c0 + li) * 512 + k * 32 + lg * 8);
            acc2[0] = MFMA16(a0, b0, acc2[0]);
            acc2[1] = MFMA16(a1, b0, acc2[1]);
        }
        float bo0 = f2b[c0 + li];
        #pragma unroll
        for (int m = 0; m < 2; m++)
            #pragma unroll
            for (int r = 0; r < 4; r++)
                yacc[0][m][r] += wgt * (acc2[m][r] + bo0);
    }
}

__global__ __launch_bounds__(256, 3) void k_mlp(
    const unsigned short* __restrict__ xn,
    const unsigned short* __restrict__ f1wb, const float* __restrict__ f1b,
    const unsigned short* __restrict__ f2wb, const float* __restrict__ f2b,
    const float* __restrict__ gw, float* __restrict__ out) {

    __shared__ unsigned short s_h[32 * 520];   // hidden bf16 [32][520]

    const int tid = threadIdx.x, wv = tid >> 6, lane = tid & 63;
    const int li = lane & 15, lg = lane >> 4;
    const int t0 = blockIdx.x * 32;
    const bool sp = (t0 >= 100352);

    const v4f z4 = {0.f, 0.f, 0.f, 0.f};
    v4f yacc[2][2];
    #pragma unroll
    for (int n = 0; n < 2; n++)
        #pragma unroll
        for (int m = 0; m < 2; m++) yacc[n][m] = z4;

    // A-fragments of xn (pass-invariant): load once
    v8s ax[2][4];
    #pragma unroll
    for (int m = 0; m < 2; m++)
        #pragma unroll
        for (int k = 0; k < 4; k++)
            ax[m][k] = *(const v8s*)(xn + (size_t)(t0 + m * 16 + li) * 128 + k * 32 + lg * 8);

    if (sp) {
        mlp_pass<4>(ax, f1wb, f1b, f2wb, f2b, gw[0], wv, li, lg, s_h, yacc);
        __syncthreads();   // protect s_h overwrite vs fc2 reads
        mlp_pass<2>(ax, f1wb, f1b, f2wb, f2b, gw[1], wv, li, lg, s_h, yacc);
        __syncthreads();
        mlp_pass<1>(ax, f1wb, f1b, f2wb, f2b, gw[2], wv, li, lg, s_h, yacc);
    } else {
        mlp_pass<4>(ax, f1wb, f1b, f2wb, f2b, 1.f, wv, li, lg, s_h, yacc);
    }

    // epilogue: out += mlp
    #pragma unroll
    for (int nt = 0; nt < 2; nt++) {
        int co = (nt * 4 + wv) * 16 + li;
        #pragma unroll
        for (int m = 0; m < 2; m++)
            #pragma unroll
            for (int r = 0; r < 4; r++) {
                size_t oi = (size_t)(t0 + m * 16 + lg * 4 + r) * 128 + co;
                out[oi] += yacc[nt][m][r];
            }
    }
}

// ---------------------------------------------------------------------------
extern "C" void kernel_launch(void* const* d_in, const int* in_sizes, int n_in,
                              void* d_out, int out_size, void* d_ws, size_t ws_size,
                              hipStream_t stream) {
    const float* x      = (const float*)d_in[0];
    const float* gw     = (const float*)d_in[1];
    const float* n1w    = (const float*)d_in[2];
    const float* n1b    = (const float*)d_in[3];
    const float* qkvw   = (const float*)d_in[4];
    const float* qkvb   = (const float*)d_in[5];
    const float* rbt    = (const float*)d_in[6];
    const float* pw     = (const float*)d_in[7];
    const float* pb     = (const float*)d_in[8];
    const float* amask  = (const float*)d_in[9];
    const float* n2w    = (const float*)d_in[10];
    const float* n2b    = (const float*)d_in[11];
    const float* f1w    = (const float*)d_in[12];
    const float* f1b    = (const float*)d_in[13];
    const float* f2w    = (const float*)d_in[14];
    const float* f2b    = (const float*)d_in[15];
    const int*   relidx = (const int*)d_in[16];
    float* out = (float*)d_out;

    unsigned short* xw    = (unsigned short*)d_ws;
    float*          comb  = (float*)((char*)d_ws + WS_COMB);
    unsigned short* wqkv  = (unsigned short*)((char*)d_ws + WS_WQKV);
    unsigned short* wproj = (unsigned short*)((char*)d_ws + WS_WPROJ);
    unsigned short* f1wb  = (unsigned short*)((char*)d_ws + WS_F1W);
    unsigned short* f2wb  = (unsigned short*)((char*)d_ws + WS_F2W);
    unsigned short* xn    = (unsigned short*)d_ws;   // aliases xw (dead by then)

    hipLaunchKernelGGL(k_prep, dim3(8704), dim3(256), 0, stream,
                       amask, rbt, relidx, qkvw, pw, f1w, f2w,
                       comb, wqkv, wproj, f1wb, f2wb, xw);
    hipLaunchKernelGGL(k_ln1, dim3(NTOK / 4), dim3(256), 0, stream, x, n1w, n1b, xw);
    hipLaunchKernelGGL(k_attn, dim3(NWIN), dim3(256), 0, stream,
                       xw, wqkv, qkvb, comb, wproj, pb, gw, x, out);
    hipLaunchKernelGGL(k_ln2, dim3(NTOK / 4), dim3(256), 0, stream, out, n2w, n2b, xn);
    hipLaunchKernelGGL(k_mlp, dim3(NTOK / 32), dim3(256), 0, stream,
                       xn, f1wb, f1b, f2wb, f2b, gw, out);
}